// Round 8
// baseline (244.905 us; speedup 1.0000x reference)
//
#include <hip/hip_runtime.h>
#include <math.h>

#define BATCH 2
#define SEQ   2048
#define DIM   1024
#define NH    16
#define HD    64
#define MTOT  4096

typedef __attribute__((ext_vector_type(8)))  short bf16x8;
typedef __attribute__((ext_vector_type(4)))  float f32x4;
typedef __attribute__((ext_vector_type(16))) float f32x16;

__device__ __forceinline__ ushort f2bf(float f) {
    union { float f; unsigned u; } v; v.f = f;
    unsigned r = v.u + 0x7fffu + ((v.u >> 16) & 1u);
    return (ushort)(r >> 16);
}

__device__ __forceinline__ unsigned cvtpk_bf16(float lo, float hi) {
    unsigned r;
    asm("v_cvt_pk_bf16_f32 %0, %1, %2" : "=v"(r) : "v"(lo), "v"(hi));
    return r;
}

// ---------------------------------------------------------------------------
// fused cast: z=0 x (4M f4), z=1..4 Wq/Wk/Wv/Wo (1M f4 each)
// ---------------------------------------------------------------------------
__global__ __launch_bounds__(256)
void cast_all(const float* __restrict__ x,
              const float* __restrict__ Wq, const float* __restrict__ Wk,
              const float* __restrict__ Wv, const float* __restrict__ Wo,
              ushort* __restrict__ xb,
              ushort* __restrict__ wqb, ushort* __restrict__ wkb,
              ushort* __restrict__ wvb, ushort* __restrict__ wob)
{
    const int z = blockIdx.y;
    const float* s; ushort* d; int n4;
    if (z == 0)      { s = x;  d = xb;  n4 = MTOT * DIM / 4; }
    else if (z == 1) { s = Wq; d = wqb; n4 = DIM * DIM / 4; }
    else if (z == 2) { s = Wk; d = wkb; n4 = DIM * DIM / 4; }
    else if (z == 3) { s = Wv; d = wvb; n4 = DIM * DIM / 4; }
    else             { s = Wo; d = wob; n4 = DIM * DIM / 4; }
    for (int i = blockIdx.x * blockDim.x + threadIdx.x; i < n4;
         i += gridDim.x * blockDim.x) {
        float4 v = ((const float4*)s)[i];
        ushort4 o;
        o.x = f2bf(v.x); o.y = f2bf(v.y); o.z = f2bf(v.z); o.w = f2bf(v.w);
        ((ushort4*)d)[i] = o;
    }
}

// ---------------------------------------------------------------------------
// bf16 NT GEMM (R3 pipeline). MODE 0 scatters into FRAGMENT-MAJOR layouts:
//   z=0 Q*0.125, z=1 K:  chunk = ((t>>5)*8 + (d>>3))*32 + (t&31), elem d&7
//   z=2 V^T:             chunk = (t>>3)*64 + d,                  elem t&7
// MODE 1: fp32 [M,N] + bias.
// ---------------------------------------------------------------------------
template<int MODE>
__global__ __launch_bounds__(256)
void gemm_bf16(const ushort* __restrict__ A,
               const ushort* __restrict__ W0, const ushort* __restrict__ W1,
               const ushort* __restrict__ W2,
               ushort* __restrict__ D0, ushort* __restrict__ D1,
               ushort* __restrict__ D2,
               const float* __restrict__ bias, float* __restrict__ Fout)
{
    __shared__ __align__(16) ushort As[2][128 * 64];
    __shared__ __align__(16) ushort Bs[2][128 * 64];

    const int tid = threadIdx.x;
    const int w = tid >> 6, l = tid & 63;
    const int g = l >> 4, l15 = l & 15;
    const int wr = w >> 1, wc = w & 1;
    const int brow = blockIdx.x * 128, bcol = blockIdx.y * 128;

    const ushort* W = (MODE == 1) ? W0
                    : (blockIdx.z == 0 ? W0 : (blockIdx.z == 1 ? W1 : W2));
    ushort* Dst = (MODE == 1) ? (ushort*)0
                : (blockIdx.z == 0 ? D0 : (blockIdx.z == 1 ? D1 : D2));

    const int rsub = l >> 3;
    const int gc   = ((l & 7) ^ rsub) * 8;
    const size_t arow0 = (size_t)(brow + 32 * w + rsub) * DIM;
    const size_t brow0 = (size_t)(bcol + 32 * w + rsub) * DIM;

    auto STAGE = [&](int buf, int ktel) {
        #pragma unroll
        for (int i = 0; i < 4; ++i) {
            __builtin_amdgcn_global_load_lds(
                (const __attribute__((address_space(1))) void*)
                    &A[arow0 + (size_t)(8 * i) * DIM + ktel + gc],
                (__attribute__((address_space(3))) void*)
                    &As[buf][(32 * w + 8 * i) * 64], 16, 0, 0);
            __builtin_amdgcn_global_load_lds(
                (const __attribute__((address_space(1))) void*)
                    &W[brow0 + (size_t)(8 * i) * DIM + ktel + gc],
                (__attribute__((address_space(3))) void*)
                    &Bs[buf][(32 * w + 8 * i) * 64], 16, 0, 0);
        }
    };

    STAGE(0, 0);
    STAGE(1, 64);

    f32x4 acc[4][4] = {};

    for (int t = 0; t < 16; ++t) {
        const int cur = t & 1;
        if (t < 15) asm volatile("s_waitcnt vmcnt(8)" ::: "memory");
        else        asm volatile("s_waitcnt vmcnt(0)" ::: "memory");
        __builtin_amdgcn_s_barrier();
        __builtin_amdgcn_sched_barrier(0);

        #pragma unroll
        for (int kh = 0; kh < 2; ++kh) {
            bf16x8 af[4], bfr[4];
            #pragma unroll
            for (int mi = 0; mi < 4; ++mi) {
                int row = 64 * wr + 16 * mi + l15;
                af[mi] = *(const bf16x8*)&As[cur][row * 64 + (((4 * kh + g) ^ (row & 7)) * 8)];
            }
            #pragma unroll
            for (int nj = 0; nj < 4; ++nj) {
                int row = 64 * wc + 16 * nj + l15;
                bfr[nj] = *(const bf16x8*)&Bs[cur][row * 64 + (((4 * kh + g) ^ (row & 7)) * 8)];
            }
            __builtin_amdgcn_s_setprio(1);
            #pragma unroll
            for (int mi = 0; mi < 4; ++mi)
                #pragma unroll
                for (int nj = 0; nj < 4; ++nj)
                    acc[mi][nj] = __builtin_amdgcn_mfma_f32_16x16x32_bf16(
                        af[mi], bfr[nj], acc[mi][nj], 0, 0, 0);
            __builtin_amdgcn_s_setprio(0);
        }

        __builtin_amdgcn_sched_barrier(0);
        __builtin_amdgcn_s_barrier();
        if (t + 2 < 16) STAGE(cur, (t + 2) * 64);
    }

    if (MODE == 0) {
        const float osc = (blockIdx.z == 0) ? 0.125f : 1.0f;
        if (blockIdx.z == 2) {
            #pragma unroll
            for (int mi = 0; mi < 4; ++mi)
                #pragma unroll
                for (int nj = 0; nj < 4; ++nj)
                    #pragma unroll
                    for (int reg = 0; reg < 4; ++reg) {
                        int row = brow + 64 * wr + 16 * mi + 4 * g + reg;
                        int col = bcol + 64 * wc + 16 * nj + l15;
                        int b = row >> 11, t = row & (SEQ - 1);
                        int hh = col >> 6, hd = col & 63;
                        Dst[(size_t)(b * NH + hh) * SEQ * HD
                            + ((size_t)(t >> 3) * 64 + hd) * 8 + (t & 7)] =
                            f2bf(acc[mi][nj][reg]);
                    }
        } else {
            #pragma unroll
            for (int mi = 0; mi < 4; ++mi)
                #pragma unroll
                for (int nj = 0; nj < 4; ++nj)
                    #pragma unroll
                    for (int reg = 0; reg < 4; ++reg) {
                        int row = brow + 64 * wr + 16 * mi + 4 * g + reg;
                        int col = bcol + 64 * wc + 16 * nj + l15;
                        int b = row >> 11, t = row & (SEQ - 1);
                        int hh = col >> 6, hd = col & 63;
                        Dst[(size_t)(b * NH + hh) * SEQ * HD
                            + (((size_t)(t >> 5) * 8 + (hd >> 3)) * 32 + (t & 31)) * 8
                            + (hd & 7)] = f2bf(acc[mi][nj][reg] * osc);
                    }
        }
    } else {
        #pragma unroll
        for (int nj = 0; nj < 4; ++nj) {
            int col = bcol + 64 * wc + 16 * nj + l15;
            float bv = bias[col];
            #pragma unroll
            for (int mi = 0; mi < 4; ++mi)
                #pragma unroll
                for (int reg = 0; reg < 4; ++reg) {
                    int row = brow + 64 * wr + 16 * mi + 4 * g + reg;
                    Fout[(size_t)row * DIM + col] = acc[mi][nj][reg] + bv;
                }
        }
    }
}

// ---------------------------------------------------------------------------
// Flash attention v6: split-KV across 4 waves per block. Block = (bh, qt),
// 256 thr; wave w handles kv tiles [w*cnt, min(nt,(w+1)*cnt)), cnt=ceil(nt/4)
// -> longest serial chain 32 -> 8 bodies. Per-wave body = v5 (reg-dbuf K,V,
// coalesced fragment-major loads, defer-max, cvt_pk+shfl P). LSE-merge
// across waves in LDS (bank-swizzled q^(d&31)), coalesced bf16 output.
// ---------------------------------------------------------------------------
__global__ __launch_bounds__(256, 4)
void attn_mfma6(const ushort* __restrict__ q, const ushort* __restrict__ k,
                const ushort* __restrict__ vt, ushort* __restrict__ ctx)
{
    __shared__ float Olds[4 * 2048];     // [w][d][q^(d&31)]  32 KB
    __shared__ float Mlds[4][32];
    __shared__ float Llds[4][32];

    const int tid = threadIdx.x;
    const int wq = tid >> 6, l = tid & 63;
    const int l31 = l & 31, h = l >> 5;
    const int bh = blockIdx.x;                // 0..31: XCD affinity = bh%8
    const int qt = 63 - (int)blockIdx.y;      // longest-first
    const int qlo = qt * 32;
    const int nt  = (qt >> 1) + 1;
    const int cnt = (nt + 3) >> 2;
    const int kt0 = wq * cnt;
    const int kt1 = min(nt, kt0 + cnt);
    const float LOG2E = 1.44269504f;

    const ushort* Qg = q  + (size_t)bh * SEQ * HD;
    const ushort* Kg = k  + (size_t)bh * SEQ * HD;
    const ushort* Vg = vt + (size_t)bh * SEQ * HD;

    // Q B-frags: coalesced chunk ((qt*8 + 2s+h)*32 + l31)
    bf16x8 qf[4];
    #pragma unroll
    for (int s = 0; s < 4; ++s)
        qf[s] = *(const bf16x8*)&Qg[(((size_t)qt * 8 + 2 * s + h) * 32 + l31) * 8];

    f32x16 o[2] = {};
    float m = -3.0e38f, lsum = 0.f;

    if (kt0 < kt1) {
        bf16x8 kfA[8], kfB[8], vfA[8], vfB[8];
        #pragma unroll
        for (int s = 0; s < 4; ++s)
            #pragma unroll
            for (int f = 0; f < 2; ++f)
                kfA[2 * s + f] = *(const bf16x8*)
                    &Kg[(((size_t)(2 * kt0 + f) * 8 + 2 * s + h) * 32 + l31) * 8];
        #pragma unroll
        for (int s4 = 0; s4 < 4; ++s4)
            #pragma unroll
            for (int dt = 0; dt < 2; ++dt)
                vfA[2 * s4 + dt] = *(const bf16x8*)
                    &Vg[(((size_t)(8 * kt0 + 2 * s4 + h)) * 64 + 32 * dt + l31) * 8];

        auto body = [&](bf16x8 (&kc)[8], bf16x8 (&kn)[8],
                        bf16x8 (&vc)[8], bf16x8 (&vn)[8], int kt) {
            const int kvb = 64 * kt;

            // S^T = K · Q^T
            f32x16 st[2] = {};
            #pragma unroll
            for (int s = 0; s < 4; ++s)
                #pragma unroll
                for (int f = 0; f < 2; ++f)
                    st[f] = __builtin_amdgcn_mfma_f32_32x32x16_bf16(
                        kc[2 * s + f], qf[s], st[f], 0, 0, 0);

            // prefetch next K and V tiles
            if (kt + 1 < kt1) {
                #pragma unroll
                for (int s = 0; s < 4; ++s)
                    #pragma unroll
                    for (int f = 0; f < 2; ++f)
                        kn[2 * s + f] = *(const bf16x8*)
                            &Kg[(((size_t)(2 * kt + 2 + f) * 8 + 2 * s + h) * 32 + l31) * 8];
                #pragma unroll
                for (int s4 = 0; s4 < 4; ++s4)
                    #pragma unroll
                    for (int dt = 0; dt < 2; ++dt)
                        vn[2 * s4 + dt] = *(const bf16x8*)
                            &Vg[(((size_t)(8 * kt + 8 + 2 * s4 + h)) * 64 + 32 * dt + l31) * 8];
            }

            // causal mask (only straddling tile)
            const int qg = qlo + l31;
            if (kvb + 63 > qlo) {
                #pragma unroll
                for (int f = 0; f < 2; ++f)
                    #pragma unroll
                    for (int r = 0; r < 16; ++r) {
                        int kvg = kvb + 32 * f + (r & 3) + 8 * (r >> 2) + 4 * h;
                        if (kvg > qg) st[f][r] = -INFINITY;
                    }
            }

            // row max, tree
            float mx[8];
            #pragma unroll
            for (int i2 = 0; i2 < 8; ++i2) {
                const int f = i2 >> 2, rb = 4 * (i2 & 3);
                mx[i2] = fmaxf(fmaxf(st[f][rb], st[f][rb + 1]),
                               fmaxf(st[f][rb + 2], st[f][rb + 3]));
            }
            float tmax = fmaxf(fmaxf(fmaxf(mx[0], mx[1]), fmaxf(mx[2], mx[3])),
                               fmaxf(fmaxf(mx[4], mx[5]), fmaxf(mx[6], mx[7])));
            tmax = fmaxf(tmax, __shfl_xor(tmax, 32));
            float ty = fmaxf(tmax * LOG2E, -3.0e38f);

            if (!__all(ty - m <= 8.0f)) {            // T13 defer-max
                float mn = fmaxf(m, ty);
                float sc = exp2f(m - mn);
                lsum *= sc;
                #pragma unroll
                for (int dt = 0; dt < 2; ++dt)
                    #pragma unroll
                    for (int r = 0; r < 16; ++r) o[dt][r] *= sc;
                m = mn;
            }

            // exp + partial sums
            float ls0 = 0.f, ls1 = 0.f, ls2 = 0.f, ls3 = 0.f;
            #pragma unroll
            for (int f = 0; f < 2; ++f)
                #pragma unroll
                for (int r = 0; r < 16; ++r) {
                    float pv = exp2f(fmaf(st[f][r], LOG2E, -m));
                    st[f][r] = pv;
                    if ((r & 3) == 0) ls0 += pv;
                    else if ((r & 3) == 1) ls1 += pv;
                    else if ((r & 3) == 2) ls2 += pv;
                    else ls3 += pv;
                }
            lsum += (ls0 + ls1) + (ls2 + ls3);

            // P -> PA frags (cvt_pk + half-wave exchange), PV MFMAs
            #pragma unroll
            for (int s4 = 0; s4 < 4; ++s4) {
                const int f = s4 >> 1, rb2 = 8 * (s4 & 1);
                unsigned Aa = cvtpk_bf16(st[f][rb2 + 0], st[f][rb2 + 1]);
                unsigned Bb = cvtpk_bf16(st[f][rb2 + 2], st[f][rb2 + 3]);
                unsigned Cc = cvtpk_bf16(st[f][rb2 + 4], st[f][rb2 + 5]);
                unsigned Dd = cvtpk_bf16(st[f][rb2 + 6], st[f][rb2 + 7]);
                unsigned Ax = (unsigned)__shfl_xor((int)Aa, 32);
                unsigned Bx = (unsigned)__shfl_xor((int)Bb, 32);
                unsigned Cx = (unsigned)__shfl_xor((int)Cc, 32);
                unsigned Dx = (unsigned)__shfl_xor((int)Dd, 32);
                union { unsigned wv[4]; bf16x8 v; } pu;
                pu.wv[0] = h ? Cx : Aa;
                pu.wv[1] = h ? Dx : Bb;
                pu.wv[2] = h ? Cc : Ax;
                pu.wv[3] = h ? Dd : Bx;
                #pragma unroll
                for (int dt = 0; dt < 2; ++dt)
                    o[dt] = __builtin_amdgcn_mfma_f32_32x32x16_bf16(
                        vc[2 * s4 + dt], pu.v, o[dt], 0, 0, 0);
            }
        };

        int kt = kt0;
        while (true) {
            body(kfA, kfB, vfA, vfB, kt);
            if (++kt >= kt1) break;
            body(kfB, kfA, vfB, vfA, kt);
            if (++kt >= kt1) break;
        }
    }

    // ---- LSE merge across the block's 4 waves ----
    float lt = lsum + __shfl_xor(lsum, 32);
    if (h == 0) Mlds[wq][l31] = m;
    __syncthreads();
    float ms = fmaxf(fmaxf(Mlds[0][l31], Mlds[1][l31]),
                     fmaxf(Mlds[2][l31], Mlds[3][l31]));
    float fw = exp2f(m - ms);
    if (h == 0) Llds[wq][l31] = lt * fw;
    #pragma unroll
    for (int dt = 0; dt < 2; ++dt)
        #pragma unroll
        for (int r = 0; r < 16; ++r) {
            int d = 32 * dt + (r & 3) + 8 * (r >> 2) + 4 * h;
            Olds[wq * 2048 + d * 32 + (l31 ^ (d & 31))] = o[dt][r] * fw;
        }
    __syncthreads();

    // combine + coalesced write: thread -> (q = tid>>3, d-chunk = tid&7)
    const int tq = tid >> 3, tc = tid & 7;
    float inv = 1.0f / (Llds[0][tq] + Llds[1][tq] + Llds[2][tq] + Llds[3][tq]);
    union { ushort u[8]; int4 v4; } ov;
    #pragma unroll
    for (int i = 0; i < 8; i += 2) {
        int d0 = 8 * tc + i, d1 = d0 + 1;
        float s0 = 0.f, s1 = 0.f;
        #pragma unroll
        for (int ww = 0; ww < 4; ++ww) {
            s0 += Olds[ww * 2048 + d0 * 32 + (tq ^ (d0 & 31))];
            s1 += Olds[ww * 2048 + d1 * 32 + (tq ^ (d1 & 31))];
        }
        *(unsigned*)&ov.u[i] = cvtpk_bf16(s0 * inv, s1 * inv);
    }
    ushort* Cg = ctx + (size_t)bh * SEQ * HD + (size_t)qlo * HD;
    *(int4*)&Cg[tq * 64 + 8 * tc] = ov.v4;
}

// ---------------------------------------------------------------------------
extern "C" void kernel_launch(void* const* d_in, const int* in_sizes, int n_in,
                              void* d_out, int out_size, void* d_ws, size_t ws_size,
                              hipStream_t stream)
{
    (void)in_sizes; (void)n_in; (void)out_size; (void)ws_size;
    const float* x  = (const float*)d_in[0];
    const float* Wq = (const float*)d_in[1];
    const float* Wk = (const float*)d_in[2];
    const float* Wv = (const float*)d_in[3];
    const float* Wo = (const float*)d_in[4];
    const float* bo = (const float*)d_in[5];
    float* out = (float*)d_out;

    ushort* wsu  = (ushort*)d_ws;
    ushort* xb   = wsu;                      // 4M
    ushort* wqb  = wsu + 4194304;            // 1M each
    ushort* wkb  = wsu + 5242880;
    ushort* wvb  = wsu + 6291456;
    ushort* wob  = wsu + 7340032;
    ushort* qbuf = wsu + 8388608;            // 4M, Q fragment-major, *0.125
    ushort* kbuf = wsu + 12582912;           // 4M, K fragment-major
    ushort* vtb  = wsu + 16777216;           // 4M, V^T fragment-major
    ushort* ctxb = wsu + 20971520;           // 4M, flat == [B*T, D]

    cast_all<<<dim3(512, 5), 256, 0, stream>>>(x, Wq, Wk, Wv, Wo,
                                               xb, wqb, wkb, wvb, wob);

    dim3 gqkv(MTOT / 128, DIM / 128, 3);
    gemm_bf16<0><<<gqkv, 256, 0, stream>>>(xb, wqb, wkb, wvb,
                                           qbuf, kbuf, vtb, nullptr, nullptr);

    dim3 ga(BATCH * NH, SEQ / 32);
    attn_mfma6<<<ga, 256, 0, stream>>>(qbuf, kbuf, vtb, ctxb);

    dim3 go(MTOT / 128, DIM / 128, 1);
    gemm_bf16<1><<<go, 256, 0, stream>>>(ctxb, wob, nullptr, nullptr,
                                         nullptr, nullptr, nullptr, bo, out);
}

// Round 9
// 110.751 us; speedup vs baseline: 2.2113x; 2.2113x over previous
//
#include <hip/hip_runtime.h>
#include <math.h>

#define BATCH 2
#define SEQ   2048
#define DIM   1024
#define NH    16
#define HD    64
#define MTOT  4096

typedef __attribute__((ext_vector_type(8)))  short bf16x8;
typedef __attribute__((ext_vector_type(4)))  float f32x4;
typedef __attribute__((ext_vector_type(16))) float f32x16;

__device__ __forceinline__ ushort f2bf(float f) {
    union { float f; unsigned u; } v; v.f = f;
    unsigned r = v.u + 0x7fffu + ((v.u >> 16) & 1u);
    return (ushort)(r >> 16);
}

__device__ __forceinline__ unsigned cvtpk_bf16(float lo, float hi) {
    unsigned r;
    asm("v_cvt_pk_bf16_f32 %0, %1, %2" : "=v"(r) : "v"(lo), "v"(hi));
    return r;
}

// ---------------------------------------------------------------------------
// fused cast: z=0 x (4M f4), z=1..4 Wq/Wk/Wv/Wo (1M f4 each)
// ---------------------------------------------------------------------------
__global__ __launch_bounds__(256)
void cast_all(const float* __restrict__ x,
              const float* __restrict__ Wq, const float* __restrict__ Wk,
              const float* __restrict__ Wv, const float* __restrict__ Wo,
              ushort* __restrict__ xb,
              ushort* __restrict__ wqb, ushort* __restrict__ wkb,
              ushort* __restrict__ wvb, ushort* __restrict__ wob)
{
    const int z = blockIdx.y;
    const float* s; ushort* d; int n4;
    if (z == 0)      { s = x;  d = xb;  n4 = MTOT * DIM / 4; }
    else if (z == 1) { s = Wq; d = wqb; n4 = DIM * DIM / 4; }
    else if (z == 2) { s = Wk; d = wkb; n4 = DIM * DIM / 4; }
    else if (z == 3) { s = Wv; d = wvb; n4 = DIM * DIM / 4; }
    else             { s = Wo; d = wob; n4 = DIM * DIM / 4; }
    for (int i = blockIdx.x * blockDim.x + threadIdx.x; i < n4;
         i += gridDim.x * blockDim.x) {
        float4 v = ((const float4*)s)[i];
        ushort4 o;
        o.x = f2bf(v.x); o.y = f2bf(v.y); o.z = f2bf(v.z); o.w = f2bf(v.w);
        ((ushort4*)d)[i] = o;
    }
}

// ---------------------------------------------------------------------------
// bf16 NT GEMM (R3 pipeline). MODE 0 scatters into FRAGMENT-MAJOR layouts:
//   z=0 Q*0.125, z=1 K:  chunk = ((t>>5)*8 + (d>>3))*32 + (t&31), elem d&7
//   z=2 V^T:             chunk = (t>>3)*64 + d,                  elem t&7
// MODE 1: fp32 [M,N] + bias.
// ---------------------------------------------------------------------------
template<int MODE>
__global__ __launch_bounds__(256)
void gemm_bf16(const ushort* __restrict__ A,
               const ushort* __restrict__ W0, const ushort* __restrict__ W1,
               const ushort* __restrict__ W2,
               ushort* __restrict__ D0, ushort* __restrict__ D1,
               ushort* __restrict__ D2,
               const float* __restrict__ bias, float* __restrict__ Fout)
{
    __shared__ __align__(16) ushort As[2][128 * 64];
    __shared__ __align__(16) ushort Bs[2][128 * 64];

    const int tid = threadIdx.x;
    const int w = tid >> 6, l = tid & 63;
    const int g = l >> 4, l15 = l & 15;
    const int wr = w >> 1, wc = w & 1;
    const int brow = blockIdx.x * 128, bcol = blockIdx.y * 128;

    const ushort* W = (MODE == 1) ? W0
                    : (blockIdx.z == 0 ? W0 : (blockIdx.z == 1 ? W1 : W2));
    ushort* Dst = (MODE == 1) ? (ushort*)0
                : (blockIdx.z == 0 ? D0 : (blockIdx.z == 1 ? D1 : D2));

    const int rsub = l >> 3;
    const int gc   = ((l & 7) ^ rsub) * 8;
    const size_t arow0 = (size_t)(brow + 32 * w + rsub) * DIM;
    const size_t brow0 = (size_t)(bcol + 32 * w + rsub) * DIM;

    auto STAGE = [&](int buf, int ktel) {
        #pragma unroll
        for (int i = 0; i < 4; ++i) {
            __builtin_amdgcn_global_load_lds(
                (const __attribute__((address_space(1))) void*)
                    &A[arow0 + (size_t)(8 * i) * DIM + ktel + gc],
                (__attribute__((address_space(3))) void*)
                    &As[buf][(32 * w + 8 * i) * 64], 16, 0, 0);
            __builtin_amdgcn_global_load_lds(
                (const __attribute__((address_space(1))) void*)
                    &W[brow0 + (size_t)(8 * i) * DIM + ktel + gc],
                (__attribute__((address_space(3))) void*)
                    &Bs[buf][(32 * w + 8 * i) * 64], 16, 0, 0);
        }
    };

    STAGE(0, 0);
    STAGE(1, 64);

    f32x4 acc[4][4] = {};

    for (int t = 0; t < 16; ++t) {
        const int cur = t & 1;
        if (t < 15) asm volatile("s_waitcnt vmcnt(8)" ::: "memory");
        else        asm volatile("s_waitcnt vmcnt(0)" ::: "memory");
        __builtin_amdgcn_s_barrier();
        __builtin_amdgcn_sched_barrier(0);

        #pragma unroll
        for (int kh = 0; kh < 2; ++kh) {
            bf16x8 af[4], bfr[4];
            #pragma unroll
            for (int mi = 0; mi < 4; ++mi) {
                int row = 64 * wr + 16 * mi + l15;
                af[mi] = *(const bf16x8*)&As[cur][row * 64 + (((4 * kh + g) ^ (row & 7)) * 8)];
            }
            #pragma unroll
            for (int nj = 0; nj < 4; ++nj) {
                int row = 64 * wc + 16 * nj + l15;
                bfr[nj] = *(const bf16x8*)&Bs[cur][row * 64 + (((4 * kh + g) ^ (row & 7)) * 8)];
            }
            __builtin_amdgcn_s_setprio(1);
            #pragma unroll
            for (int mi = 0; mi < 4; ++mi)
                #pragma unroll
                for (int nj = 0; nj < 4; ++nj)
                    acc[mi][nj] = __builtin_amdgcn_mfma_f32_16x16x32_bf16(
                        af[mi], bfr[nj], acc[mi][nj], 0, 0, 0);
            __builtin_amdgcn_s_setprio(0);
        }

        __builtin_amdgcn_sched_barrier(0);
        __builtin_amdgcn_s_barrier();
        if (t + 2 < 16) STAGE(cur, (t + 2) * 64);
    }

    if (MODE == 0) {
        const float osc = (blockIdx.z == 0) ? 0.125f : 1.0f;
        if (blockIdx.z == 2) {
            #pragma unroll
            for (int mi = 0; mi < 4; ++mi)
                #pragma unroll
                for (int nj = 0; nj < 4; ++nj)
                    #pragma unroll
                    for (int reg = 0; reg < 4; ++reg) {
                        int row = brow + 64 * wr + 16 * mi + 4 * g + reg;
                        int col = bcol + 64 * wc + 16 * nj + l15;
                        int b = row >> 11, t = row & (SEQ - 1);
                        int hh = col >> 6, hd = col & 63;
                        Dst[(size_t)(b * NH + hh) * SEQ * HD
                            + ((size_t)(t >> 3) * 64 + hd) * 8 + (t & 7)] =
                            f2bf(acc[mi][nj][reg]);
                    }
        } else {
            #pragma unroll
            for (int mi = 0; mi < 4; ++mi)
                #pragma unroll
                for (int nj = 0; nj < 4; ++nj)
                    #pragma unroll
                    for (int reg = 0; reg < 4; ++reg) {
                        int row = brow + 64 * wr + 16 * mi + 4 * g + reg;
                        int col = bcol + 64 * wc + 16 * nj + l15;
                        int b = row >> 11, t = row & (SEQ - 1);
                        int hh = col >> 6, hd = col & 63;
                        Dst[(size_t)(b * NH + hh) * SEQ * HD
                            + (((size_t)(t >> 5) * 8 + (hd >> 3)) * 32 + (t & 31)) * 8
                            + (hd & 7)] = f2bf(acc[mi][nj][reg] * osc);
                    }
        }
    } else {
        #pragma unroll
        for (int nj = 0; nj < 4; ++nj) {
            int col = bcol + 64 * wc + 16 * nj + l15;
            float bv = bias[col];
            #pragma unroll
            for (int mi = 0; mi < 4; ++mi)
                #pragma unroll
                for (int reg = 0; reg < 4; ++reg) {
                    int row = brow + 64 * wr + 16 * mi + 4 * g + reg;
                    Fout[(size_t)row * DIM + col] = acc[mi][nj][reg] + bv;
                }
        }
    }
}

// ---------------------------------------------------------------------------
// Flash attention v7 = v6 with the register cap fixed: __launch_bounds__
// (256, 2) -> 256-VGPR budget, no spills (R8's (256,4) forced 128 -> 64 VGPR
// and 780 MB of scratch traffic). Split-KV across 4 waves, LSE merge in LDS,
// longest-first dispatch + queue backfill.
// ---------------------------------------------------------------------------
__global__ __launch_bounds__(256, 2)
void attn_mfma7(const ushort* __restrict__ q, const ushort* __restrict__ k,
                const ushort* __restrict__ vt, ushort* __restrict__ ctx)
{
    __shared__ float Olds[4 * 2048];     // [w][d][q^(d&31)]  32 KB
    __shared__ float Mlds[4][32];
    __shared__ float Llds[4][32];

    const int tid = threadIdx.x;
    const int wq = tid >> 6, l = tid & 63;
    const int l31 = l & 31, h = l >> 5;
    const int bh = blockIdx.x;                // 0..31: XCD affinity = bh%8
    const int qt = 63 - (int)blockIdx.y;      // longest-first
    const int qlo = qt * 32;
    const int nt  = (qt >> 1) + 1;
    const int cnt = (nt + 3) >> 2;
    const int kt0 = wq * cnt;
    const int kt1 = min(nt, kt0 + cnt);
    const float LOG2E = 1.44269504f;

    const ushort* Qg = q  + (size_t)bh * SEQ * HD;
    const ushort* Kg = k  + (size_t)bh * SEQ * HD;
    const ushort* Vg = vt + (size_t)bh * SEQ * HD;

    // Q B-frags: coalesced chunk ((qt*8 + 2s+h)*32 + l31)
    bf16x8 qf[4];
    #pragma unroll
    for (int s = 0; s < 4; ++s)
        qf[s] = *(const bf16x8*)&Qg[(((size_t)qt * 8 + 2 * s + h) * 32 + l31) * 8];

    f32x16 o[2] = {};
    float m = -3.0e38f, lsum = 0.f;

    if (kt0 < kt1) {
        bf16x8 kfA[8], kfB[8], vfA[8], vfB[8];
        #pragma unroll
        for (int s = 0; s < 4; ++s)
            #pragma unroll
            for (int f = 0; f < 2; ++f)
                kfA[2 * s + f] = *(const bf16x8*)
                    &Kg[(((size_t)(2 * kt0 + f) * 8 + 2 * s + h) * 32 + l31) * 8];
        #pragma unroll
        for (int s4 = 0; s4 < 4; ++s4)
            #pragma unroll
            for (int dt = 0; dt < 2; ++dt)
                vfA[2 * s4 + dt] = *(const bf16x8*)
                    &Vg[(((size_t)(8 * kt0 + 2 * s4 + h)) * 64 + 32 * dt + l31) * 8];

        auto body = [&](bf16x8 (&kc)[8], bf16x8 (&kn)[8],
                        bf16x8 (&vc)[8], bf16x8 (&vn)[8], int kt) {
            const int kvb = 64 * kt;

            // S^T = K · Q^T
            f32x16 st[2] = {};
            #pragma unroll
            for (int s = 0; s < 4; ++s)
                #pragma unroll
                for (int f = 0; f < 2; ++f)
                    st[f] = __builtin_amdgcn_mfma_f32_32x32x16_bf16(
                        kc[2 * s + f], qf[s], st[f], 0, 0, 0);

            // prefetch next K and V tiles
            if (kt + 1 < kt1) {
                #pragma unroll
                for (int s = 0; s < 4; ++s)
                    #pragma unroll
                    for (int f = 0; f < 2; ++f)
                        kn[2 * s + f] = *(const bf16x8*)
                            &Kg[(((size_t)(2 * kt + 2 + f) * 8 + 2 * s + h) * 32 + l31) * 8];
                #pragma unroll
                for (int s4 = 0; s4 < 4; ++s4)
                    #pragma unroll
                    for (int dt = 0; dt < 2; ++dt)
                        vn[2 * s4 + dt] = *(const bf16x8*)
                            &Vg[(((size_t)(8 * kt + 8 + 2 * s4 + h)) * 64 + 32 * dt + l31) * 8];
            }

            // causal mask (only straddling tile)
            const int qg = qlo + l31;
            if (kvb + 63 > qlo) {
                #pragma unroll
                for (int f = 0; f < 2; ++f)
                    #pragma unroll
                    for (int r = 0; r < 16; ++r) {
                        int kvg = kvb + 32 * f + (r & 3) + 8 * (r >> 2) + 4 * h;
                        if (kvg > qg) st[f][r] = -INFINITY;
                    }
            }

            // row max, tree
            float mx[8];
            #pragma unroll
            for (int i2 = 0; i2 < 8; ++i2) {
                const int f = i2 >> 2, rb = 4 * (i2 & 3);
                mx[i2] = fmaxf(fmaxf(st[f][rb], st[f][rb + 1]),
                               fmaxf(st[f][rb + 2], st[f][rb + 3]));
            }
            float tmax = fmaxf(fmaxf(fmaxf(mx[0], mx[1]), fmaxf(mx[2], mx[3])),
                               fmaxf(fmaxf(mx[4], mx[5]), fmaxf(mx[6], mx[7])));
            tmax = fmaxf(tmax, __shfl_xor(tmax, 32));
            float ty = fmaxf(tmax * LOG2E, -3.0e38f);

            if (!__all(ty - m <= 8.0f)) {            // T13 defer-max
                float mn = fmaxf(m, ty);
                float sc = exp2f(m - mn);
                lsum *= sc;
                #pragma unroll
                for (int dt = 0; dt < 2; ++dt)
                    #pragma unroll
                    for (int r = 0; r < 16; ++r) o[dt][r] *= sc;
                m = mn;
            }

            // exp + partial sums
            float ls0 = 0.f, ls1 = 0.f, ls2 = 0.f, ls3 = 0.f;
            #pragma unroll
            for (int f = 0; f < 2; ++f)
                #pragma unroll
                for (int r = 0; r < 16; ++r) {
                    float pv = exp2f(fmaf(st[f][r], LOG2E, -m));
                    st[f][r] = pv;
                    if ((r & 3) == 0) ls0 += pv;
                    else if ((r & 3) == 1) ls1 += pv;
                    else if ((r & 3) == 2) ls2 += pv;
                    else ls3 += pv;
                }
            lsum += (ls0 + ls1) + (ls2 + ls3);

            // P -> PA frags (cvt_pk + half-wave exchange), PV MFMAs
            #pragma unroll
            for (int s4 = 0; s4 < 4; ++s4) {
                const int f = s4 >> 1, rb2 = 8 * (s4 & 1);
                unsigned Aa = cvtpk_bf16(st[f][rb2 + 0], st[f][rb2 + 1]);
                unsigned Bb = cvtpk_bf16(st[f][rb2 + 2], st[f][rb2 + 3]);
                unsigned Cc = cvtpk_bf16(st[f][rb2 + 4], st[f][rb2 + 5]);
                unsigned Dd = cvtpk_bf16(st[f][rb2 + 6], st[f][rb2 + 7]);
                unsigned Ax = (unsigned)__shfl_xor((int)Aa, 32);
                unsigned Bx = (unsigned)__shfl_xor((int)Bb, 32);
                unsigned Cx = (unsigned)__shfl_xor((int)Cc, 32);
                unsigned Dx = (unsigned)__shfl_xor((int)Dd, 32);
                union { unsigned wv[4]; bf16x8 v; } pu;
                pu.wv[0] = h ? Cx : Aa;
                pu.wv[1] = h ? Dx : Bb;
                pu.wv[2] = h ? Cc : Ax;
                pu.wv[3] = h ? Dd : Bx;
                #pragma unroll
                for (int dt = 0; dt < 2; ++dt)
                    o[dt] = __builtin_amdgcn_mfma_f32_32x32x16_bf16(
                        vc[2 * s4 + dt], pu.v, o[dt], 0, 0, 0);
            }
        };

        int kt = kt0;
        while (true) {
            body(kfA, kfB, vfA, vfB, kt);
            if (++kt >= kt1) break;
            body(kfB, kfA, vfB, vfA, kt);
            if (++kt >= kt1) break;
        }
    }

    // ---- LSE merge across the block's 4 waves ----
    float lt = lsum + __shfl_xor(lsum, 32);
    if (h == 0) Mlds[wq][l31] = m;
    __syncthreads();
    float ms = fmaxf(fmaxf(Mlds[0][l31], Mlds[1][l31]),
                     fmaxf(Mlds[2][l31], Mlds[3][l31]));
    float fw = exp2f(m - ms);
    if (h == 0) Llds[wq][l31] = lt * fw;
    #pragma unroll
    for (int dt = 0; dt < 2; ++dt)
        #pragma unroll
        for (int r = 0; r < 16; ++r) {
            int d = 32 * dt + (r & 3) + 8 * (r >> 2) + 4 * h;
            Olds[wq * 2048 + d * 32 + (l31 ^ (d & 31))] = o[dt][r] * fw;
        }
    __syncthreads();

    // combine + coalesced write: thread -> (q = tid>>3, d-chunk = tid&7)
    const int tq = tid >> 3, tc = tid & 7;
    float inv = 1.0f / (Llds[0][tq] + Llds[1][tq] + Llds[2][tq] + Llds[3][tq]);
    union { ushort u[8]; int4 v4; } ov;
    #pragma unroll
    for (int i = 0; i < 8; i += 2) {
        int d0 = 8 * tc + i, d1 = d0 + 1;
        float s0 = 0.f, s1 = 0.f;
        #pragma unroll
        for (int ww = 0; ww < 4; ++ww) {
            s0 += Olds[ww * 2048 + d0 * 32 + (tq ^ (d0 & 31))];
            s1 += Olds[ww * 2048 + d1 * 32 + (tq ^ (d1 & 31))];
        }
        *(unsigned*)&ov.u[i] = cvtpk_bf16(s0 * inv, s1 * inv);
    }
    ushort* Cg = ctx + (size_t)bh * SEQ * HD + (size_t)qlo * HD;
    *(int4*)&Cg[tq * 64 + 8 * tc] = ov.v4;
}

// ---------------------------------------------------------------------------
extern "C" void kernel_launch(void* const* d_in, const int* in_sizes, int n_in,
                              void* d_out, int out_size, void* d_ws, size_t ws_size,
                              hipStream_t stream)
{
    (void)in_sizes; (void)n_in; (void)out_size; (void)ws_size;
    const float* x  = (const float*)d_in[0];
    const float* Wq = (const float*)d_in[1];
    const float* Wk = (const float*)d_in[2];
    const float* Wv = (const float*)d_in[3];
    const float* Wo = (const float*)d_in[4];
    const float* bo = (const float*)d_in[5];
    float* out = (float*)d_out;

    ushort* wsu  = (ushort*)d_ws;
    ushort* xb   = wsu;                      // 4M
    ushort* wqb  = wsu + 4194304;            // 1M each
    ushort* wkb  = wsu + 5242880;
    ushort* wvb  = wsu + 6291456;
    ushort* wob  = wsu + 7340032;
    ushort* qbuf = wsu + 8388608;            // 4M, Q fragment-major, *0.125
    ushort* kbuf = wsu + 12582912;           // 4M, K fragment-major
    ushort* vtb  = wsu + 16777216;           // 4M, V^T fragment-major
    ushort* ctxb = wsu + 20971520;           // 4M, flat == [B*T, D]

    cast_all<<<dim3(512, 5), 256, 0, stream>>>(x, Wq, Wk, Wv, Wo,
                                               xb, wqb, wkb, wvb, wob);

    dim3 gqkv(MTOT / 128, DIM / 128, 3);
    gemm_bf16<0><<<gqkv, 256, 0, stream>>>(xb, wqb, wkb, wvb,
                                           qbuf, kbuf, vtb, nullptr, nullptr);

    dim3 ga(BATCH * NH, SEQ / 32);
    attn_mfma7<<<ga, 256, 0, stream>>>(qbuf, kbuf, vtb, ctxb);

    dim3 go(MTOT / 128, DIM / 128, 1);
    gemm_bf16<1><<<go, 256, 0, stream>>>(ctxb, wob, nullptr, nullptr,
                                         nullptr, nullptr, nullptr, bo, out);
}

// Round 10
// 107.767 us; speedup vs baseline: 2.2725x; 1.0277x over previous
//
#include <hip/hip_runtime.h>
#include <math.h>

#define BATCH 2
#define SEQ   2048
#define DIM   1024
#define NH    16
#define HD    64
#define MTOT  4096

typedef __attribute__((ext_vector_type(8)))  short bf16x8;
typedef __attribute__((ext_vector_type(4)))  float f32x4;
typedef __attribute__((ext_vector_type(16))) float f32x16;
typedef __attribute__((ext_vector_type(2)))  unsigned u32x2;

__device__ __forceinline__ ushort f2bf(float f) {
    union { float f; unsigned u; } v; v.f = f;
    unsigned r = v.u + 0x7fffu + ((v.u >> 16) & 1u);
    return (ushort)(r >> 16);
}

__device__ __forceinline__ unsigned cvtpk_bf16(float lo, float hi) {
    unsigned r;
    asm("v_cvt_pk_bf16_f32 %0, %1, %2" : "=v"(r) : "v"(lo), "v"(hi));
    return r;
}

// ---------------------------------------------------------------------------
// fused cast: z=0 x (4M f4), z=1..4 Wq/Wk/Wv/Wo (1M f4 each)
// ---------------------------------------------------------------------------
__global__ __launch_bounds__(256)
void cast_all(const float* __restrict__ x,
              const float* __restrict__ Wq, const float* __restrict__ Wk,
              const float* __restrict__ Wv, const float* __restrict__ Wo,
              ushort* __restrict__ xb,
              ushort* __restrict__ wqb, ushort* __restrict__ wkb,
              ushort* __restrict__ wvb, ushort* __restrict__ wob)
{
    const int z = blockIdx.y;
    const float* s; ushort* d; int n4;
    if (z == 0)      { s = x;  d = xb;  n4 = MTOT * DIM / 4; }
    else if (z == 1) { s = Wq; d = wqb; n4 = DIM * DIM / 4; }
    else if (z == 2) { s = Wk; d = wkb; n4 = DIM * DIM / 4; }
    else if (z == 3) { s = Wv; d = wvb; n4 = DIM * DIM / 4; }
    else             { s = Wo; d = wob; n4 = DIM * DIM / 4; }
    for (int i = blockIdx.x * blockDim.x + threadIdx.x; i < n4;
         i += gridDim.x * blockDim.x) {
        float4 v = ((const float4*)s)[i];
        ushort4 o;
        o.x = f2bf(v.x); o.y = f2bf(v.y); o.z = f2bf(v.z); o.w = f2bf(v.w);
        ((ushort4*)d)[i] = o;
    }
}

// ---------------------------------------------------------------------------
// bf16 NT GEMM (R3 pipeline). MODE 0 writes FRAGMENT-MAJOR layouts via a
// 32KB LDS bounce (reusing As after the final barrier) -> fully coalesced
// dwordx4 stores instead of 2-byte scatters:
//   z=0 Q*0.125, z=1 K:  elem = ((t>>5)*8+(d>>3))*256 + (t&31)*8 + (d&7)
//   z=2 V^T:             elem = ((t>>3)*64+d)*8 + (t&7)
// MODE 1: fp32 [M,N] + bias (direct stores, 64B-segment coalesced).
// ---------------------------------------------------------------------------
template<int MODE>
__global__ __launch_bounds__(256)
void gemm_bf16(const ushort* __restrict__ A,
               const ushort* __restrict__ W0, const ushort* __restrict__ W1,
               const ushort* __restrict__ W2,
               ushort* __restrict__ D0, ushort* __restrict__ D1,
               ushort* __restrict__ D2,
               const float* __restrict__ bias, float* __restrict__ Fout)
{
    __shared__ __align__(16) ushort As[2][128 * 64];
    __shared__ __align__(16) ushort Bs[2][128 * 64];

    const int tid = threadIdx.x;
    const int w = tid >> 6, l = tid & 63;
    const int g = l >> 4, l15 = l & 15;
    const int wr = w >> 1, wc = w & 1;
    const int brow = blockIdx.x * 128, bcol = blockIdx.y * 128;

    const ushort* W = (MODE == 1) ? W0
                    : (blockIdx.z == 0 ? W0 : (blockIdx.z == 1 ? W1 : W2));
    ushort* Dst = (MODE == 1) ? (ushort*)0
                : (blockIdx.z == 0 ? D0 : (blockIdx.z == 1 ? D1 : D2));

    const int rsub = l >> 3;
    const int gc   = ((l & 7) ^ rsub) * 8;
    const size_t arow0 = (size_t)(brow + 32 * w + rsub) * DIM;
    const size_t brow0 = (size_t)(bcol + 32 * w + rsub) * DIM;

    auto STAGE = [&](int buf, int ktel) {
        #pragma unroll
        for (int i = 0; i < 4; ++i) {
            __builtin_amdgcn_global_load_lds(
                (const __attribute__((address_space(1))) void*)
                    &A[arow0 + (size_t)(8 * i) * DIM + ktel + gc],
                (__attribute__((address_space(3))) void*)
                    &As[buf][(32 * w + 8 * i) * 64], 16, 0, 0);
            __builtin_amdgcn_global_load_lds(
                (const __attribute__((address_space(1))) void*)
                    &W[brow0 + (size_t)(8 * i) * DIM + ktel + gc],
                (__attribute__((address_space(3))) void*)
                    &Bs[buf][(32 * w + 8 * i) * 64], 16, 0, 0);
        }
    };

    STAGE(0, 0);
    STAGE(1, 64);

    f32x4 acc[4][4] = {};

    for (int t = 0; t < 16; ++t) {
        const int cur = t & 1;
        if (t < 15) asm volatile("s_waitcnt vmcnt(8)" ::: "memory");
        else        asm volatile("s_waitcnt vmcnt(0)" ::: "memory");
        __builtin_amdgcn_s_barrier();
        __builtin_amdgcn_sched_barrier(0);

        #pragma unroll
        for (int kh = 0; kh < 2; ++kh) {
            bf16x8 af[4], bfr[4];
            #pragma unroll
            for (int mi = 0; mi < 4; ++mi) {
                int row = 64 * wr + 16 * mi + l15;
                af[mi] = *(const bf16x8*)&As[cur][row * 64 + (((4 * kh + g) ^ (row & 7)) * 8)];
            }
            #pragma unroll
            for (int nj = 0; nj < 4; ++nj) {
                int row = 64 * wc + 16 * nj + l15;
                bfr[nj] = *(const bf16x8*)&Bs[cur][row * 64 + (((4 * kh + g) ^ (row & 7)) * 8)];
            }
            __builtin_amdgcn_s_setprio(1);
            #pragma unroll
            for (int mi = 0; mi < 4; ++mi)
                #pragma unroll
                for (int nj = 0; nj < 4; ++nj)
                    acc[mi][nj] = __builtin_amdgcn_mfma_f32_16x16x32_bf16(
                        af[mi], bfr[nj], acc[mi][nj], 0, 0, 0);
            __builtin_amdgcn_s_setprio(0);
        }

        __builtin_amdgcn_sched_barrier(0);
        __builtin_amdgcn_s_barrier();
        if (t + 2 < 16) STAGE(cur, (t + 2) * 64);
    }

    if (MODE == 0) {
        ushort* LB = (ushort*)As;                    // 32 KB bounce
        const int bB = brow >> 11, t0 = brow & (SEQ - 1);
        if (blockIdx.z == 2) {
            // V^T: LDS elem = ((tg*2+hh)*64 + hd)*8 + (t&7); b64-packed writes
            #pragma unroll
            for (int mi = 0; mi < 4; ++mi)
                #pragma unroll
                for (int nj = 0; nj < 4; ++nj) {
                    int tlb = 64 * wr + 16 * mi + 4 * g;
                    int hd = 16 * nj + l15;
                    int sI = (tlb >> 3) * 2 + wc;
                    uint2 pk;
                    pk.x = cvtpk_bf16(acc[mi][nj][0], acc[mi][nj][1]);
                    pk.y = cvtpk_bf16(acc[mi][nj][2], acc[mi][nj][3]);
                    *(uint2*)&LB[sI * 512 + hd * 8 + (tlb & 7)] = pk;
                }
            __syncthreads();
            #pragma unroll
            for (int j = 0; j < 8; ++j) {
                int4 v = *(const int4*)&LB[(j * 256 + tid) * 8];
                int sI = j * 4 + (tid >> 6);
                size_t base = (size_t)(bB * NH + 2 * blockIdx.y + (sI & 1)) * (SEQ * HD)
                            + (size_t)((t0 >> 3) + (sI >> 1)) * 512 + (tid & 63) * 8;
                *(int4*)&Dst[base] = v;
            }
        } else {
            const float osc = (blockIdx.z == 0) ? 0.125f : 1.0f;
            // Q/K: LDS elem = ((tg*2+hh)*8 + hd>>3)*256 + (t&31)*8 + (d&7)
            #pragma unroll
            for (int mi = 0; mi < 4; ++mi)
                #pragma unroll
                for (int nj = 0; nj < 4; ++nj)
                    #pragma unroll
                    for (int reg = 0; reg < 4; ++reg) {
                        int tl = 64 * wr + 16 * mi + 4 * g + reg;
                        int hd = 16 * nj + l15;
                        int sI = (tl >> 5) * 2 + wc;
                        LB[sI * 2048 + (hd >> 3) * 256 + (tl & 31) * 8 + (hd & 7)] =
                            f2bf(acc[mi][nj][reg] * osc);
                    }
            __syncthreads();
            #pragma unroll
            for (int j = 0; j < 8; ++j) {
                int4 v = *(const int4*)&LB[(j * 256 + tid) * 8];
                size_t base = (size_t)(bB * NH + 2 * blockIdx.y + (j & 1)) * (SEQ * HD)
                            + (size_t)((t0 >> 5) + (j >> 1)) * 2048 + tid * 8;
                *(int4*)&Dst[base] = v;
            }
        }
    } else {
        #pragma unroll
        for (int nj = 0; nj < 4; ++nj) {
            int col = bcol + 64 * wc + 16 * nj + l15;
            float bv = bias[col];
            #pragma unroll
            for (int mi = 0; mi < 4; ++mi)
                #pragma unroll
                for (int reg = 0; reg < 4; ++reg) {
                    int row = brow + 64 * wr + 16 * mi + 4 * g + reg;
                    Fout[(size_t)row * DIM + col] = acc[mi][nj][reg] + bv;
                }
        }
    }
}

// ---------------------------------------------------------------------------
// Flash attention v8 = v7 + permlane32_swap P-build (T12: 8 VALU permlanes
// replace 16 ds_bpermute + 16 cndmask per body) + setprio around MFMA (T5).
// Split-KV across 4 waves, LSE merge in LDS, longest-first dispatch.
// ---------------------------------------------------------------------------
__global__ __launch_bounds__(256, 2)
void attn_mfma8(const ushort* __restrict__ q, const ushort* __restrict__ k,
                const ushort* __restrict__ vt, ushort* __restrict__ ctx)
{
    __shared__ float Olds[4 * 2048];     // [w][d][q^(d&31)]  32 KB
    __shared__ float Mlds[4][32];
    __shared__ float Llds[4][32];

    const int tid = threadIdx.x;
    const int wq = tid >> 6, l = tid & 63;
    const int l31 = l & 31, h = l >> 5;
    const int bh = blockIdx.x;                // 0..31: XCD affinity = bh%8
    const int qt = 63 - (int)blockIdx.y;      // longest-first
    const int qlo = qt * 32;
    const int nt  = (qt >> 1) + 1;
    const int cnt = (nt + 3) >> 2;
    const int kt0 = wq * cnt;
    const int kt1 = min(nt, kt0 + cnt);
    const float LOG2E = 1.44269504f;

    const ushort* Qg = q  + (size_t)bh * SEQ * HD;
    const ushort* Kg = k  + (size_t)bh * SEQ * HD;
    const ushort* Vg = vt + (size_t)bh * SEQ * HD;

    bf16x8 qf[4];
    #pragma unroll
    for (int s = 0; s < 4; ++s)
        qf[s] = *(const bf16x8*)&Qg[(((size_t)qt * 8 + 2 * s + h) * 32 + l31) * 8];

    f32x16 o[2] = {};
    float m = -3.0e38f, lsum = 0.f;

    if (kt0 < kt1) {
        bf16x8 kfA[8], kfB[8], vfA[8], vfB[8];
        #pragma unroll
        for (int s = 0; s < 4; ++s)
            #pragma unroll
            for (int f = 0; f < 2; ++f)
                kfA[2 * s + f] = *(const bf16x8*)
                    &Kg[(((size_t)(2 * kt0 + f) * 8 + 2 * s + h) * 32 + l31) * 8];
        #pragma unroll
        for (int s4 = 0; s4 < 4; ++s4)
            #pragma unroll
            for (int dt = 0; dt < 2; ++dt)
                vfA[2 * s4 + dt] = *(const bf16x8*)
                    &Vg[(((size_t)(8 * kt0 + 2 * s4 + h)) * 64 + 32 * dt + l31) * 8];

        auto body = [&](bf16x8 (&kc)[8], bf16x8 (&kn)[8],
                        bf16x8 (&vc)[8], bf16x8 (&vn)[8], int kt) {
            const int kvb = 64 * kt;

            // S^T = K · Q^T
            f32x16 st[2] = {};
            __builtin_amdgcn_s_setprio(1);
            #pragma unroll
            for (int s = 0; s < 4; ++s)
                #pragma unroll
                for (int f = 0; f < 2; ++f)
                    st[f] = __builtin_amdgcn_mfma_f32_32x32x16_bf16(
                        kc[2 * s + f], qf[s], st[f], 0, 0, 0);
            __builtin_amdgcn_s_setprio(0);

            // prefetch next K and V tiles
            if (kt + 1 < kt1) {
                #pragma unroll
                for (int s = 0; s < 4; ++s)
                    #pragma unroll
                    for (int f = 0; f < 2; ++f)
                        kn[2 * s + f] = *(const bf16x8*)
                            &Kg[(((size_t)(2 * kt + 2 + f) * 8 + 2 * s + h) * 32 + l31) * 8];
                #pragma unroll
                for (int s4 = 0; s4 < 4; ++s4)
                    #pragma unroll
                    for (int dt = 0; dt < 2; ++dt)
                        vn[2 * s4 + dt] = *(const bf16x8*)
                            &Vg[(((size_t)(8 * kt + 8 + 2 * s4 + h)) * 64 + 32 * dt + l31) * 8];
            }

            // causal mask (only straddling tile)
            const int qg = qlo + l31;
            if (kvb + 63 > qlo) {
                #pragma unroll
                for (int f = 0; f < 2; ++f)
                    #pragma unroll
                    for (int r = 0; r < 16; ++r) {
                        int kvg = kvb + 32 * f + (r & 3) + 8 * (r >> 2) + 4 * h;
                        if (kvg > qg) st[f][r] = -INFINITY;
                    }
            }

            // row max, tree; half-exchange via permlane32_swap
            float mx[8];
            #pragma unroll
            for (int i2 = 0; i2 < 8; ++i2) {
                const int f = i2 >> 2, rb = 4 * (i2 & 3);
                mx[i2] = fmaxf(fmaxf(st[f][rb], st[f][rb + 1]),
                               fmaxf(st[f][rb + 2], st[f][rb + 3]));
            }
            float tmax = fmaxf(fmaxf(fmaxf(mx[0], mx[1]), fmaxf(mx[2], mx[3])),
                               fmaxf(fmaxf(mx[4], mx[5]), fmaxf(mx[6], mx[7])));
            {
                union { float f; unsigned u; } tm; tm.f = tmax;
                u32x2 ts = __builtin_amdgcn_permlane32_swap(tm.u, tm.u, false, false);
                union { unsigned u; float f; } to; to.u = h ? ts.x : ts.y;
                tmax = fmaxf(tmax, to.f);
            }
            float ty = fmaxf(tmax * LOG2E, -3.0e38f);

            if (!__all(ty - m <= 8.0f)) {            // T13 defer-max
                float mn = fmaxf(m, ty);
                float sc = exp2f(m - mn);
                lsum *= sc;
                #pragma unroll
                for (int dt = 0; dt < 2; ++dt)
                    #pragma unroll
                    for (int r = 0; r < 16; ++r) o[dt][r] *= sc;
                m = mn;
            }

            // exp + partial sums
            float ls0 = 0.f, ls1 = 0.f, ls2 = 0.f, ls3 = 0.f;
            #pragma unroll
            for (int f = 0; f < 2; ++f)
                #pragma unroll
                for (int r = 0; r < 16; ++r) {
                    float pv = exp2f(fmaf(st[f][r], LOG2E, -m));
                    st[f][r] = pv;
                    if ((r & 3) == 0) ls0 += pv;
                    else if ((r & 3) == 1) ls1 += pv;
                    else if ((r & 3) == 2) ls2 += pv;
                    else ls3 += pv;
                }
            lsum += (ls0 + ls1) + (ls2 + ls3);

            // P -> PA frags: cvt_pk + permlane32_swap (T12), PV MFMAs
            #pragma unroll
            for (int s4 = 0; s4 < 4; ++s4) {
                const int f = s4 >> 1, rb2 = 8 * (s4 & 1);
                unsigned Aa = cvtpk_bf16(st[f][rb2 + 0], st[f][rb2 + 1]);
                unsigned Bb = cvtpk_bf16(st[f][rb2 + 2], st[f][rb2 + 3]);
                unsigned Cc = cvtpk_bf16(st[f][rb2 + 4], st[f][rb2 + 5]);
                unsigned Dd = cvtpk_bf16(st[f][rb2 + 6], st[f][rb2 + 7]);
                u32x2 r02 = __builtin_amdgcn_permlane32_swap(Aa, Cc, false, false);
                u32x2 r13 = __builtin_amdgcn_permlane32_swap(Bb, Dd, false, false);
                union { unsigned wv[4]; bf16x8 v; } pu;
                pu.wv[0] = r02.x;   // h=0: A,  h=1: Cx
                pu.wv[1] = r13.x;   // h=0: B,  h=1: Dx
                pu.wv[2] = r02.y;   // h=0: Ax, h=1: C
                pu.wv[3] = r13.y;   // h=0: Bx, h=1: D
                __builtin_amdgcn_s_setprio(1);
                #pragma unroll
                for (int dt = 0; dt < 2; ++dt)
                    o[dt] = __builtin_amdgcn_mfma_f32_32x32x16_bf16(
                        vc[2 * s4 + dt], pu.v, o[dt], 0, 0, 0);
                __builtin_amdgcn_s_setprio(0);
            }
        };

        int kt = kt0;
        while (true) {
            body(kfA, kfB, vfA, vfB, kt);
            if (++kt >= kt1) break;
            body(kfB, kfA, vfB, vfA, kt);
            if (++kt >= kt1) break;
        }
    }

    // ---- LSE merge across the block's 4 waves ----
    float lt = lsum + __shfl_xor(lsum, 32);
    if (h == 0) Mlds[wq][l31] = m;
    __syncthreads();
    float ms = fmaxf(fmaxf(Mlds[0][l31], Mlds[1][l31]),
                     fmaxf(Mlds[2][l31], Mlds[3][l31]));
    float fw = exp2f(m - ms);
    if (h == 0) Llds[wq][l31] = lt * fw;
    #pragma unroll
    for (int dt = 0; dt < 2; ++dt)
        #pragma unroll
        for (int r = 0; r < 16; ++r) {
            int d = 32 * dt + (r & 3) + 8 * (r >> 2) + 4 * h;
            Olds[wq * 2048 + d * 32 + (l31 ^ (d & 31))] = o[dt][r] * fw;
        }
    __syncthreads();

    // combine + coalesced write: thread -> (q = tid>>3, d-chunk = tid&7)
    const int tq = tid >> 3, tc = tid & 7;
    float inv = 1.0f / (Llds[0][tq] + Llds[1][tq] + Llds[2][tq] + Llds[3][tq]);
    union { ushort u[8]; int4 v4; } ov;
    #pragma unroll
    for (int i = 0; i < 8; i += 2) {
        int d0 = 8 * tc + i, d1 = d0 + 1;
        float s0 = 0.f, s1 = 0.f;
        #pragma unroll
        for (int ww = 0; ww < 4; ++ww) {
            s0 += Olds[ww * 2048 + d0 * 32 + (tq ^ (d0 & 31))];
            s1 += Olds[ww * 2048 + d1 * 32 + (tq ^ (d1 & 31))];
        }
        *(unsigned*)&ov.u[i] = cvtpk_bf16(s0 * inv, s1 * inv);
    }
    ushort* Cg = ctx + (size_t)bh * SEQ * HD + (size_t)qlo * HD;
    *(int4*)&Cg[tq * 64 + 8 * tc] = ov.v4;
}

// ---------------------------------------------------------------------------
extern "C" void kernel_launch(void* const* d_in, const int* in_sizes, int n_in,
                              void* d_out, int out_size, void* d_ws, size_t ws_size,
                              hipStream_t stream)
{
    (void)in_sizes; (void)n_in; (void)out_size; (void)ws_size;
    const float* x  = (const float*)d_in[0];
    const float* Wq = (const float*)d_in[1];
    const float* Wk = (const float*)d_in[2];
    const float* Wv = (const float*)d_in[3];
    const float* Wo = (const float*)d_in[4];
    const float* bo = (const float*)d_in[5];
    float* out = (float*)d_out;

    ushort* wsu  = (ushort*)d_ws;
    ushort* xb   = wsu;                      // 4M
    ushort* wqb  = wsu + 4194304;            // 1M each
    ushort* wkb  = wsu + 5242880;
    ushort* wvb  = wsu + 6291456;
    ushort* wob  = wsu + 7340032;
    ushort* qbuf = wsu + 8388608;            // 4M, Q fragment-major, *0.125
    ushort* kbuf = wsu + 12582912;           // 4M, K fragment-major
    ushort* vtb  = wsu + 16777216;           // 4M, V^T fragment-major
    ushort* ctxb = wsu + 20971520;           // 4M, flat == [B*T, D]

    cast_all<<<dim3(512, 5), 256, 0, stream>>>(x, Wq, Wk, Wv, Wo,
                                               xb, wqb, wkb, wvb, wob);

    dim3 gqkv(MTOT / 128, DIM / 128, 3);
    gemm_bf16<0><<<gqkv, 256, 0, stream>>>(xb, wqb, wkb, wvb,
                                           qbuf, kbuf, vtb, nullptr, nullptr);

    dim3 ga(BATCH * NH, SEQ / 32);
    attn_mfma8<<<ga, 256, 0, stream>>>(qbuf, kbuf, vtb, ctxb);

    dim3 go(MTOT / 128, DIM / 128, 1);
    gemm_bf16<1><<<go, 256, 0, stream>>>(ctxb, wob, nullptr, nullptr,
                                         nullptr, nullptr, nullptr, bo, out);
}

// Round 11
// 106.876 us; speedup vs baseline: 2.2915x; 1.0083x over previous
//
#include <hip/hip_runtime.h>
#include <math.h>

#define BATCH 2
#define SEQ   2048
#define DIM   1024
#define NH    16
#define HD    64
#define MTOT  4096

typedef __attribute__((ext_vector_type(8)))  short bf16x8;
typedef __attribute__((ext_vector_type(4)))  float f32x4;
typedef __attribute__((ext_vector_type(16))) float f32x16;
typedef __attribute__((ext_vector_type(2)))  float f32x2;
typedef __attribute__((ext_vector_type(2)))  unsigned u32x2;

__device__ __forceinline__ ushort f2bf(float f) {
    union { float f; unsigned u; } v; v.f = f;
    unsigned r = v.u + 0x7fffu + ((v.u >> 16) & 1u);
    return (ushort)(r >> 16);
}

__device__ __forceinline__ unsigned cvtpk_bf16(float lo, float hi) {
    unsigned r;
    asm("v_cvt_pk_bf16_f32 %0, %1, %2" : "=v"(r) : "v"(lo), "v"(hi));
    return r;
}

__device__ __forceinline__ f32x2 pk_add(f32x2 a, f32x2 b) {
    f32x2 d;
    asm("v_pk_add_f32 %0, %1, %2" : "=v"(d) : "v"(a), "v"(b));
    return d;
}

__device__ __forceinline__ f32x2 pk_mul(f32x2 a, f32x2 b) {
    f32x2 d;
    asm("v_pk_mul_f32 %0, %1, %2" : "=v"(d) : "v"(a), "v"(b));
    return d;
}

__device__ __forceinline__ float fmax3(float a, float b, float c) {
    return fmaxf(fmaxf(a, b), c);   // clang fuses to v_max3_f32
}

// ---------------------------------------------------------------------------
// fused cast: z=0 x (4M f4), z=1..4 Wq/Wk/Wv/Wo (1M f4 each)
// ---------------------------------------------------------------------------
__global__ __launch_bounds__(256)
void cast_all(const float* __restrict__ x,
              const float* __restrict__ Wq, const float* __restrict__ Wk,
              const float* __restrict__ Wv, const float* __restrict__ Wo,
              ushort* __restrict__ xb,
              ushort* __restrict__ wqb, ushort* __restrict__ wkb,
              ushort* __restrict__ wvb, ushort* __restrict__ wob)
{
    const int z = blockIdx.y;
    const float* s; ushort* d; int n4;
    if (z == 0)      { s = x;  d = xb;  n4 = MTOT * DIM / 4; }
    else if (z == 1) { s = Wq; d = wqb; n4 = DIM * DIM / 4; }
    else if (z == 2) { s = Wk; d = wkb; n4 = DIM * DIM / 4; }
    else if (z == 3) { s = Wv; d = wvb; n4 = DIM * DIM / 4; }
    else             { s = Wo; d = wob; n4 = DIM * DIM / 4; }
    for (int i = blockIdx.x * blockDim.x + threadIdx.x; i < n4;
         i += gridDim.x * blockDim.x) {
        float4 v = ((const float4*)s)[i];
        ushort4 o;
        o.x = f2bf(v.x); o.y = f2bf(v.y); o.z = f2bf(v.z); o.w = f2bf(v.w);
        ((ushort4*)d)[i] = o;
    }
}

// ---------------------------------------------------------------------------
// bf16 NT GEMM (R3 pipeline). MODE 0 writes FRAGMENT-MAJOR layouts via a
// 32KB LDS bounce -> coalesced dwordx4 stores.
//   z=0 Q*(0.125*log2e)  (exp2-domain scores), z=1 K, z=2 V^T
// MODE 1: fp32 [M,N] + bias.
// ---------------------------------------------------------------------------
template<int MODE>
__global__ __launch_bounds__(256)
void gemm_bf16(const ushort* __restrict__ A,
               const ushort* __restrict__ W0, const ushort* __restrict__ W1,
               const ushort* __restrict__ W2,
               ushort* __restrict__ D0, ushort* __restrict__ D1,
               ushort* __restrict__ D2,
               const float* __restrict__ bias, float* __restrict__ Fout)
{
    __shared__ __align__(16) ushort As[2][128 * 64];
    __shared__ __align__(16) ushort Bs[2][128 * 64];

    const int tid = threadIdx.x;
    const int w = tid >> 6, l = tid & 63;
    const int g = l >> 4, l15 = l & 15;
    const int wr = w >> 1, wc = w & 1;
    const int brow = blockIdx.x * 128, bcol = blockIdx.y * 128;

    const ushort* W = (MODE == 1) ? W0
                    : (blockIdx.z == 0 ? W0 : (blockIdx.z == 1 ? W1 : W2));
    ushort* Dst = (MODE == 1) ? (ushort*)0
                : (blockIdx.z == 0 ? D0 : (blockIdx.z == 1 ? D1 : D2));

    const int rsub = l >> 3;
    const int gc   = ((l & 7) ^ rsub) * 8;
    const size_t arow0 = (size_t)(brow + 32 * w + rsub) * DIM;
    const size_t brow0 = (size_t)(bcol + 32 * w + rsub) * DIM;

    auto STAGE = [&](int buf, int ktel) {
        #pragma unroll
        for (int i = 0; i < 4; ++i) {
            __builtin_amdgcn_global_load_lds(
                (const __attribute__((address_space(1))) void*)
                    &A[arow0 + (size_t)(8 * i) * DIM + ktel + gc],
                (__attribute__((address_space(3))) void*)
                    &As[buf][(32 * w + 8 * i) * 64], 16, 0, 0);
            __builtin_amdgcn_global_load_lds(
                (const __attribute__((address_space(1))) void*)
                    &W[brow0 + (size_t)(8 * i) * DIM + ktel + gc],
                (__attribute__((address_space(3))) void*)
                    &Bs[buf][(32 * w + 8 * i) * 64], 16, 0, 0);
        }
    };

    STAGE(0, 0);
    STAGE(1, 64);

    f32x4 acc[4][4] = {};

    for (int t = 0; t < 16; ++t) {
        const int cur = t & 1;
        if (t < 15) asm volatile("s_waitcnt vmcnt(8)" ::: "memory");
        else        asm volatile("s_waitcnt vmcnt(0)" ::: "memory");
        __builtin_amdgcn_s_barrier();
        __builtin_amdgcn_sched_barrier(0);

        #pragma unroll
        for (int kh = 0; kh < 2; ++kh) {
            bf16x8 af[4], bfr[4];
            #pragma unroll
            for (int mi = 0; mi < 4; ++mi) {
                int row = 64 * wr + 16 * mi + l15;
                af[mi] = *(const bf16x8*)&As[cur][row * 64 + (((4 * kh + g) ^ (row & 7)) * 8)];
            }
            #pragma unroll
            for (int nj = 0; nj < 4; ++nj) {
                int row = 64 * wc + 16 * nj + l15;
                bfr[nj] = *(const bf16x8*)&Bs[cur][row * 64 + (((4 * kh + g) ^ (row & 7)) * 8)];
            }
            __builtin_amdgcn_s_setprio(1);
            #pragma unroll
            for (int mi = 0; mi < 4; ++mi)
                #pragma unroll
                for (int nj = 0; nj < 4; ++nj)
                    acc[mi][nj] = __builtin_amdgcn_mfma_f32_16x16x32_bf16(
                        af[mi], bfr[nj], acc[mi][nj], 0, 0, 0);
            __builtin_amdgcn_s_setprio(0);
        }

        __builtin_amdgcn_sched_barrier(0);
        __builtin_amdgcn_s_barrier();
        if (t + 2 < 16) STAGE(cur, (t + 2) * 64);
    }

    if (MODE == 0) {
        ushort* LB = (ushort*)As;                    // 32 KB bounce
        const int bB = brow >> 11, t0 = brow & (SEQ - 1);
        if (blockIdx.z == 2) {
            #pragma unroll
            for (int mi = 0; mi < 4; ++mi)
                #pragma unroll
                for (int nj = 0; nj < 4; ++nj) {
                    int tlb = 64 * wr + 16 * mi + 4 * g;
                    int hd = 16 * nj + l15;
                    int sI = (tlb >> 3) * 2 + wc;
                    uint2 pk;
                    pk.x = cvtpk_bf16(acc[mi][nj][0], acc[mi][nj][1]);
                    pk.y = cvtpk_bf16(acc[mi][nj][2], acc[mi][nj][3]);
                    *(uint2*)&LB[sI * 512 + hd * 8 + (tlb & 7)] = pk;
                }
            __syncthreads();
            #pragma unroll
            for (int j = 0; j < 8; ++j) {
                int4 v = *(const int4*)&LB[(j * 256 + tid) * 8];
                int sI = j * 4 + (tid >> 6);
                size_t base = (size_t)(bB * NH + 2 * blockIdx.y + (sI & 1)) * (SEQ * HD)
                            + (size_t)((t0 >> 3) + (sI >> 1)) * 512 + (tid & 63) * 8;
                *(int4*)&Dst[base] = v;
            }
        } else {
            const float osc = (blockIdx.z == 0) ? 0.125f * 1.44269504f : 1.0f;
            #pragma unroll
            for (int mi = 0; mi < 4; ++mi)
                #pragma unroll
                for (int nj = 0; nj < 4; ++nj)
                    #pragma unroll
                    for (int reg = 0; reg < 4; ++reg) {
                        int tl = 64 * wr + 16 * mi + 4 * g + reg;
                        int hd = 16 * nj + l15;
                        int sI = (tl >> 5) * 2 + wc;
                        LB[sI * 2048 + (hd >> 3) * 256 + (tl & 31) * 8 + (hd & 7)] =
                            f2bf(acc[mi][nj][reg] * osc);
                    }
            __syncthreads();
            #pragma unroll
            for (int j = 0; j < 8; ++j) {
                int4 v = *(const int4*)&LB[(j * 256 + tid) * 8];
                size_t base = (size_t)(bB * NH + 2 * blockIdx.y + (j & 1)) * (SEQ * HD)
                            + (size_t)((t0 >> 5) + (j >> 1)) * 2048 + tid * 8;
                *(int4*)&Dst[base] = v;
            }
        }
    } else {
        #pragma unroll
        for (int nj = 0; nj < 4; ++nj) {
            int col = bcol + 64 * wc + 16 * nj + l15;
            float bv = bias[col];
            #pragma unroll
            for (int mi = 0; mi < 4; ++mi)
                #pragma unroll
                for (int reg = 0; reg < 4; ++reg) {
                    int row = brow + 64 * wr + 16 * mi + 4 * g + reg;
                    Fout[(size_t)row * DIM + col] = acc[mi][nj][reg] + bv;
                }
        }
    }
}

// ---------------------------------------------------------------------------
// Flash attention v9 = v8 with VALU diet: scores arrive exp2-domain (Q
// pre-scaled by 0.125*log2e -> no fma before exp), v_max3 tree, packed-f32
// (v_pk_add/mul) for -m subtract, lsum accumulation and O-rescale.
// ---------------------------------------------------------------------------
__global__ __launch_bounds__(256, 2)
void attn_mfma9(const ushort* __restrict__ q, const ushort* __restrict__ k,
                const ushort* __restrict__ vt, ushort* __restrict__ ctx)
{
    __shared__ float Olds[4 * 2048];     // [w][d][q^(d&31)]  32 KB
    __shared__ float Mlds[4][32];
    __shared__ float Llds[4][32];

    const int tid = threadIdx.x;
    const int wq = tid >> 6, l = tid & 63;
    const int l31 = l & 31, h = l >> 5;
    const int bh = blockIdx.x;                // 0..31: XCD affinity = bh%8
    const int qt = 63 - (int)blockIdx.y;      // longest-first
    const int qlo = qt * 32;
    const int nt  = (qt >> 1) + 1;
    const int cnt = (nt + 3) >> 2;
    const int kt0 = wq * cnt;
    const int kt1 = min(nt, kt0 + cnt);

    const ushort* Qg = q  + (size_t)bh * SEQ * HD;
    const ushort* Kg = k  + (size_t)bh * SEQ * HD;
    const ushort* Vg = vt + (size_t)bh * SEQ * HD;

    bf16x8 qf[4];
    #pragma unroll
    for (int s = 0; s < 4; ++s)
        qf[s] = *(const bf16x8*)&Qg[(((size_t)qt * 8 + 2 * s + h) * 32 + l31) * 8];

    f32x16 o[2] = {};
    float m = -3.0e38f, lsum = 0.f;

    if (kt0 < kt1) {
        bf16x8 kfA[8], kfB[8], vfA[8], vfB[8];
        #pragma unroll
        for (int s = 0; s < 4; ++s)
            #pragma unroll
            for (int f = 0; f < 2; ++f)
                kfA[2 * s + f] = *(const bf16x8*)
                    &Kg[(((size_t)(2 * kt0 + f) * 8 + 2 * s + h) * 32 + l31) * 8];
        #pragma unroll
        for (int s4 = 0; s4 < 4; ++s4)
            #pragma unroll
            for (int dt = 0; dt < 2; ++dt)
                vfA[2 * s4 + dt] = *(const bf16x8*)
                    &Vg[(((size_t)(8 * kt0 + 2 * s4 + h)) * 64 + 32 * dt + l31) * 8];

        auto body = [&](bf16x8 (&kc)[8], bf16x8 (&kn)[8],
                        bf16x8 (&vc)[8], bf16x8 (&vn)[8], int kt) {
            const int kvb = 64 * kt;

            // S^T = K · Q^T  (already exp2-domain)
            f32x16 st[2] = {};
            __builtin_amdgcn_s_setprio(1);
            #pragma unroll
            for (int s = 0; s < 4; ++s)
                #pragma unroll
                for (int f = 0; f < 2; ++f)
                    st[f] = __builtin_amdgcn_mfma_f32_32x32x16_bf16(
                        kc[2 * s + f], qf[s], st[f], 0, 0, 0);
            __builtin_amdgcn_s_setprio(0);

            // prefetch next K and V tiles
            if (kt + 1 < kt1) {
                #pragma unroll
                for (int s = 0; s < 4; ++s)
                    #pragma unroll
                    for (int f = 0; f < 2; ++f)
                        kn[2 * s + f] = *(const bf16x8*)
                            &Kg[(((size_t)(2 * kt + 2 + f) * 8 + 2 * s + h) * 32 + l31) * 8];
                #pragma unroll
                for (int s4 = 0; s4 < 4; ++s4)
                    #pragma unroll
                    for (int dt = 0; dt < 2; ++dt)
                        vn[2 * s4 + dt] = *(const bf16x8*)
                            &Vg[(((size_t)(8 * kt + 8 + 2 * s4 + h)) * 64 + 32 * dt + l31) * 8];
            }

            // causal mask (only straddling tile)
            const int qg = qlo + l31;
            if (kvb + 63 > qlo) {
                #pragma unroll
                for (int f = 0; f < 2; ++f)
                    #pragma unroll
                    for (int r = 0; r < 16; ++r) {
                        int kvg = kvb + 32 * f + (r & 3) + 8 * (r >> 2) + 4 * h;
                        if (kvg > qg) st[f][r] = -INFINITY;
                    }
            }

            // row max via max3 chains (2 parallel chains per f)
            float ca, cb;
            ca = fmax3(st[0][0], st[0][1], st[0][2]);
            cb = fmax3(st[0][3], st[0][4], st[0][5]);
            ca = fmax3(ca, st[0][6], st[0][7]);
            cb = fmax3(cb, st[0][8], st[0][9]);
            ca = fmax3(ca, st[0][10], st[0][11]);
            cb = fmax3(cb, st[0][12], st[0][13]);
            ca = fmax3(ca, st[0][14], st[0][15]);
            float t0 = fmaxf(ca, cb);
            ca = fmax3(st[1][0], st[1][1], st[1][2]);
            cb = fmax3(st[1][3], st[1][4], st[1][5]);
            ca = fmax3(ca, st[1][6], st[1][7]);
            cb = fmax3(cb, st[1][8], st[1][9]);
            ca = fmax3(ca, st[1][10], st[1][11]);
            cb = fmax3(cb, st[1][12], st[1][13]);
            ca = fmax3(ca, st[1][14], st[1][15]);
            float tmax = fmax3(t0, ca, cb);
            {
                union { float f; unsigned u; } tm; tm.f = tmax;
                u32x2 ts = __builtin_amdgcn_permlane32_swap(tm.u, tm.u, false, false);
                union { unsigned u; float f; } to; to.u = h ? ts.x : ts.y;
                tmax = fmaxf(tmax, to.f);
            }

            if (!__all(tmax - m <= 8.0f)) {          // T13 defer-max (log2 dom)
                float mn = fmaxf(m, tmax);
                float sc = exp2f(m - mn);
                lsum *= sc;
                f32x2 sc2 = {sc, sc};
                #pragma unroll
                for (int dt = 0; dt < 2; ++dt) {
                    f32x2* po = (f32x2*)&o[dt];
                    #pragma unroll
                    for (int i = 0; i < 8; ++i) po[i] = pk_mul(po[i], sc2);
                }
                m = mn;
            }

            // exp + packed sums: t = pk_add(pair, {-m,-m}); exp2; pk-accumulate
            f32x2 mneg = {-m, -m};
            f32x2 a0 = {0.f, 0.f}, a1 = {0.f, 0.f}, a2 = {0.f, 0.f}, a3 = {0.f, 0.f};
            #pragma unroll
            for (int f = 0; f < 2; ++f) {
                f32x2* pp = (f32x2*)&st[f];
                #pragma unroll
                for (int i = 0; i < 8; ++i) {
                    f32x2 t = pk_add(pp[i], mneg);
                    t.x = exp2f(t.x); t.y = exp2f(t.y);
                    pp[i] = t;
                    if ((i & 3) == 0)      a0 = pk_add(a0, t);
                    else if ((i & 3) == 1) a1 = pk_add(a1, t);
                    else if ((i & 3) == 2) a2 = pk_add(a2, t);
                    else                   a3 = pk_add(a3, t);
                }
            }
            a0 = pk_add(a0, a1);
            a2 = pk_add(a2, a3);
            a0 = pk_add(a0, a2);
            lsum += a0.x + a0.y;

            // P -> PA frags: cvt_pk + permlane32_swap (T12), PV MFMAs
            #pragma unroll
            for (int s4 = 0; s4 < 4; ++s4) {
                const int f = s4 >> 1, rb2 = 8 * (s4 & 1);
                unsigned Aa = cvtpk_bf16(st[f][rb2 + 0], st[f][rb2 + 1]);
                unsigned Bb = cvtpk_bf16(st[f][rb2 + 2], st[f][rb2 + 3]);
                unsigned Cc = cvtpk_bf16(st[f][rb2 + 4], st[f][rb2 + 5]);
                unsigned Dd = cvtpk_bf16(st[f][rb2 + 6], st[f][rb2 + 7]);
                u32x2 r02 = __builtin_amdgcn_permlane32_swap(Aa, Cc, false, false);
                u32x2 r13 = __builtin_amdgcn_permlane32_swap(Bb, Dd, false, false);
                union { unsigned wv[4]; bf16x8 v; } pu;
                pu.wv[0] = r02.x;
                pu.wv[1] = r13.x;
                pu.wv[2] = r02.y;
                pu.wv[3] = r13.y;
                __builtin_amdgcn_s_setprio(1);
                #pragma unroll
                for (int dt = 0; dt < 2; ++dt)
                    o[dt] = __builtin_amdgcn_mfma_f32_32x32x16_bf16(
                        vc[2 * s4 + dt], pu.v, o[dt], 0, 0, 0);
                __builtin_amdgcn_s_setprio(0);
            }
        };

        int kt = kt0;
        while (true) {
            body(kfA, kfB, vfA, vfB, kt);
            if (++kt >= kt1) break;
            body(kfB, kfA, vfB, vfA, kt);
            if (++kt >= kt1) break;
        }
    }

    // ---- LSE merge across the block's 4 waves ----
    float lt = lsum + __shfl_xor(lsum, 32);
    if (h == 0) Mlds[wq][l31] = m;
    __syncthreads();
    float ms = fmaxf(fmaxf(Mlds[0][l31], Mlds[1][l31]),
                     fmaxf(Mlds[2][l31], Mlds[3][l31]));
    float fw = exp2f(m - ms);
    if (h == 0) Llds[wq][l31] = lt * fw;
    #pragma unroll
    for (int dt = 0; dt < 2; ++dt)
        #pragma unroll
        for (int r = 0; r < 16; ++r) {
            int d = 32 * dt + (r & 3) + 8 * (r >> 2) + 4 * h;
            Olds[wq * 2048 + d * 32 + (l31 ^ (d & 31))] = o[dt][r] * fw;
        }
    __syncthreads();

    // combine + coalesced write: thread -> (q = tid>>3, d-chunk = tid&7)
    const int tq = tid >> 3, tc = tid & 7;
    float inv = 1.0f / (Llds[0][tq] + Llds[1][tq] + Llds[2][tq] + Llds[3][tq]);
    union { ushort u[8]; int4 v4; } ov;
    #pragma unroll
    for (int i = 0; i < 8; i += 2) {
        int d0 = 8 * tc + i, d1 = d0 + 1;
        float s0 = 0.f, s1 = 0.f;
        #pragma unroll
        for (int ww = 0; ww < 4; ++ww) {
            s0 += Olds[ww * 2048 + d0 * 32 + (tq ^ (d0 & 31))];
            s1 += Olds[ww * 2048 + d1 * 32 + (tq ^ (d1 & 31))];
        }
        *(unsigned*)&ov.u[i] = cvtpk_bf16(s0 * inv, s1 * inv);
    }
    ushort* Cg = ctx + (size_t)bh * SEQ * HD + (size_t)qlo * HD;
    *(int4*)&Cg[tq * 64 + 8 * tc] = ov.v4;
}

// ---------------------------------------------------------------------------
extern "C" void kernel_launch(void* const* d_in, const int* in_sizes, int n_in,
                              void* d_out, int out_size, void* d_ws, size_t ws_size,
                              hipStream_t stream)
{
    (void)in_sizes; (void)n_in; (void)out_size; (void)ws_size;
    const float* x  = (const float*)d_in[0];
    const float* Wq = (const float*)d_in[1];
    const float* Wk = (const float*)d_in[2];
    const float* Wv = (const float*)d_in[3];
    const float* Wo = (const float*)d_in[4];
    const float* bo = (const float*)d_in[5];
    float* out = (float*)d_out;

    ushort* wsu  = (ushort*)d_ws;
    ushort* xb   = wsu;                      // 4M
    ushort* wqb  = wsu + 4194304;            // 1M each
    ushort* wkb  = wsu + 5242880;
    ushort* wvb  = wsu + 6291456;
    ushort* wob  = wsu + 7340032;
    ushort* qbuf = wsu + 8388608;            // 4M, Q fragment-major, *0.125*log2e
    ushort* kbuf = wsu + 12582912;           // 4M, K fragment-major
    ushort* vtb  = wsu + 16777216;           // 4M, V^T fragment-major
    ushort* ctxb = wsu + 20971520;           // 4M, flat == [B*T, D]

    cast_all<<<dim3(512, 5), 256, 0, stream>>>(x, Wq, Wk, Wv, Wo,
                                               xb, wqb, wkb, wvb, wob);

    dim3 gqkv(MTOT / 128, DIM / 128, 3);
    gemm_bf16<0><<<gqkv, 256, 0, stream>>>(xb, wqb, wkb, wvb,
                                           qbuf, kbuf, vtb, nullptr, nullptr);

    dim3 ga(BATCH * NH, SEQ / 32);
    attn_mfma9<<<ga, 256, 0, stream>>>(qbuf, kbuf, vtb, ctxb);

    dim3 go(MTOT / 128, DIM / 128, 1);
    gemm_bf16<1><<<go, 256, 0, stream>>>(ctxb, wob, nullptr, nullptr,
                                         nullptr, nullptr, nullptr, bo, out);
}